// Round 17
// baseline (49.964 us; speedup 1.0000x reference)
//
#include <hip/hip_runtime.h>
#include <math.h>

#define HW (1024*1024)
#define BATCH 16
#define FLAG_MAGIC 0x5AFE5AFEu

// Single launch, spin-gated producer design (no block barrier between params
// and workers — R3/R7/R16 proved any intra-block rendezvous loses):
//   block 0 (dispatched FIRST -> resident immediately; never waits on anyone
//     => deadlock-free): computes the 192 param floats -> par (d_ws), then
//     __threadfence + release-stores FLAG_MAGIC.
//   blocks 1..1024: issue their 8 weight dwordx4 loads, then acquire-spin on
//     the flag (hidden under the ~900cy HBM load latency; on replays the flag
//     is already MAGIC -> no wait at all; producer re-writing IDENTICAL par
//     values is a benign race). Poison value 0xAAAAAAAA != MAGIC, so the
//     first post-poison replay also waits for its own producer => correct
//     output on EVERY call.
// Math fold: caddmul(clerp(w0,w1,l), s, bias) = w0*s*(1-l) + w1*s*l + bias,
// so A = s*(1-l), B = s*l, C = bias. par: [16][2][6] = {Ar,Ai,Br,Bi,Cr,Ci}
__global__ __launch_bounds__(256) void fused_spin_kernel(
    const float* __restrict__ x,       // [16][64]
    const float* __restrict__ W_in,    // [12][64]
    const float* __restrict__ b_in,    // [12]
    const float* __restrict__ W_gate,  // [12][64]
    const float* __restrict__ b_gate,  // [12]
    const float* __restrict__ wts,     // [2][2][HW][2]
    float* __restrict__ out,           // [16][HW]
    float* __restrict__ par,           // [16][2][6] in d_ws
    unsigned int* __restrict__ flag)   // in d_ws, after par
{
    __shared__ float smod[BATCH][12];
    const int t = threadIdx.x;
    const int bid = blockIdx.x;

    if (bid == 0) {
        // ---- producer block ----
        if (t < 192) {
            int b = t / 12, j = t % 12;
            const float4* x4  = (const float4*)(x + b * 64);
            const float4* wi4 = (const float4*)(W_in + j * 64);
            const float4* wg4 = (const float4*)(W_gate + j * 64);
            float xt = b_in[j], xg = b_gate[j];
#pragma unroll
            for (int k = 0; k < 16; ++k) {
                float4 xv = x4[k], wi = wi4[k], wg = wg4[k];
                xt = fmaf(xv.x, wi.x, xt); xg = fmaf(xv.x, wg.x, xg);
                xt = fmaf(xv.y, wi.y, xt); xg = fmaf(xv.y, wg.y, xg);
                xt = fmaf(xv.z, wi.z, xt); xg = fmaf(xv.z, wg.z, xg);
                xt = fmaf(xv.w, wi.w, xt); xg = fmaf(xv.w, wg.w, xg);
            }
            smod[b][j] = xt * tanhf(xg);
        }
        __syncthreads();
        if (t < 32) {                    // lanes 0..31 of wave 0
            int bb = t >> 1, c = t & 1;
            float l0 = smod[bb][0 + c * 2 + 0] + 0.5f;
            float l1 = smod[bb][0 + c * 2 + 1];
            float br = smod[bb][4 + c * 2 + 0];
            float bi = smod[bb][4 + c * 2 + 1];
            float s0 = smod[bb][8 + c * 2 + 0] + 1.0f;
            float s1 = smod[bb][8 + c * 2 + 1];
            float omr = 1.0f - l0, omi = -l1;    // (1 - l)
            float Ar = s0 * omr - s1 * omi;
            float Ai = s0 * omi + s1 * omr;
            float Br = s0 * l0 - s1 * l1;
            float Bi = s0 * l1 + s1 * l0;
            float* p = par + t * 6;              // t == bb*2 + c
            p[0] = Ar; p[1] = Ai; p[2] = Br; p[3] = Bi; p[4] = br; p[5] = bi;
        }
        // wave 0 wrote par; same-wave fence orders those stores before flag
        __threadfence();
        if (t == 0)
            __hip_atomic_store(flag, FLAG_MAGIC, __ATOMIC_RELEASE,
                               __HIP_MEMORY_SCOPE_AGENT);
        return;
    }

    // ---- worker blocks ----
    const int idx = (bid - 1) * 256 + t;     // 0 .. HW/4 - 1 (4 px/thread)
    const float4* w4 = (const float4*)wts;   // [jc][HW/2] float4s

    float4 Wv[4][2];
#pragma unroll
    for (int jc = 0; jc < 4; ++jc) {
        Wv[jc][0] = w4[jc * (HW / 2) + idx * 2 + 0];
        Wv[jc][1] = w4[jc * (HW / 2) + idx * 2 + 1];
    }

    // spin until params are published (first call only; afterwards flag
    // stays MAGIC and this falls through immediately)
    while (__hip_atomic_load(flag, __ATOMIC_ACQUIRE,
                             __HIP_MEMORY_SCOPE_AGENT) != FLAG_MAGIC) {
        __builtin_amdgcn_s_sleep(8);
    }

    const float* w00 = (const float*)Wv[0];  // j=0, c=0
    const float* w01 = (const float*)Wv[1];  // j=0, c=1
    const float* w10 = (const float*)Wv[2];  // j=1, c=0
    const float* w11 = (const float*)Wv[3];  // j=1, c=1

    float4* out4 = (float4*)out;
#pragma unroll
    for (int b = 0; b < BATCH; ++b) {
        const float* p0 = par + (b * 2 + 0) * 6;   // uniform -> scalar loads
        const float* p1 = par + (b * 2 + 1) * 6;
        float A0r = p0[0], A0i = p0[1], B0r = p0[2], B0i = p0[3], c0r = p0[4], c0i = p0[5];
        float A1r = p1[0], A1i = p1[1], B1r = p1[2], B1i = p1[3], c1r = p1[4], c1i = p1[5];

        float4 o;
        float* op = (float*)&o;
#pragma unroll
        for (int p = 0; p < 4; ++p) {
            float a0r = w00[p * 2], a0i = w00[p * 2 + 1];
            float b0r = w10[p * 2], b0i = w10[p * 2 + 1];
            float a1r = w01[p * 2], a1i = w01[p * 2 + 1];
            float b1r = w11[p * 2], b1i = w11[p * 2 + 1];
            float z0r = c0r + A0r * a0r - A0i * a0i + B0r * b0r - B0i * b0i;
            float z0i = c0i + A0r * a0i + A0i * a0r + B0r * b0i + B0i * b0r;
            float z1r = c1r + A1r * a1r - A1i * a1i + B1r * b1r - B1i * b1i;
            float z1i = c1i + A1r * a1i + A1i * a1r + B1r * b1i + B1i * b1r;
            // raw v_rsq_f32 (validated R16: absmax 3.9e-3 << 1.24e-2)
            float rs = __builtin_amdgcn_rsqf(z1r * z1r + z1i * z1i + 1e-12f);
            op[p] = (z0r * z1r + z0i * z1i) * rs;
        }
        out4[b * (HW / 4) + idx] = o;
    }
}

extern "C" void kernel_launch(void* const* d_in, const int* in_sizes, int n_in,
                              void* d_out, int out_size, void* d_ws, size_t ws_size,
                              hipStream_t stream) {
    const float* x      = (const float*)d_in[0];
    const float* W_in   = (const float*)d_in[1];
    const float* b_in   = (const float*)d_in[2];
    const float* W_gate = (const float*)d_in[3];
    const float* b_gate = (const float*)d_in[4];
    const float* wts    = (const float*)d_in[5];
    float* out = (float*)d_out;
    float* par = (float*)d_ws;
    unsigned int* flag = (unsigned int*)((char*)d_ws + 1024);

    fused_spin_kernel<<<1025, 256, 0, stream>>>(x, W_in, b_in, W_gate, b_gate,
                                                wts, out, par, flag);
}

// Round 18
// 27.128 us; speedup vs baseline: 1.8418x; 1.8418x over previous
//
#include <hip/hip_runtime.h>
#include <math.h>

#define HW (1024*1024)
#define BATCH 16

typedef float fx4 __attribute__((ext_vector_type(4)));

// Kernel 1: per-(batch,channel) complex affine params -> d_ws (768 B).
// Fold: caddmul(clerp(w0,w1,l), s, bias) = w0*s*(1-l) + w1*s*l + bias,
// so A = s*(1-l), B = s*l, C = bias.  par: [16][2][6] = {Ar,Ai,Br,Bi,Cr,Ci}
__global__ __launch_bounds__(192) void params_kernel(
    const float* __restrict__ x,       // [16][64]
    const float* __restrict__ W_in,    // [12][64]
    const float* __restrict__ b_in,    // [12]
    const float* __restrict__ W_gate,  // [12][64]
    const float* __restrict__ b_gate,  // [12]
    float* __restrict__ par)           // [16][2][6]
{
    __shared__ float smod[BATCH][12];
    int t = threadIdx.x;
    int b = t / 12, j = t % 12;
    {
        const float4* x4  = (const float4*)(x + b * 64);
        const float4* wi4 = (const float4*)(W_in + j * 64);
        const float4* wg4 = (const float4*)(W_gate + j * 64);
        float xt = b_in[j], xg = b_gate[j];
#pragma unroll
        for (int k = 0; k < 16; ++k) {
            float4 xv = x4[k], wi = wi4[k], wg = wg4[k];
            xt = fmaf(xv.x, wi.x, xt); xg = fmaf(xv.x, wg.x, xg);
            xt = fmaf(xv.y, wi.y, xt); xg = fmaf(xv.y, wg.y, xg);
            xt = fmaf(xv.z, wi.z, xt); xg = fmaf(xv.z, wg.z, xg);
            xt = fmaf(xv.w, wi.w, xt); xg = fmaf(xv.w, wg.w, xg);
        }
        smod[b][j] = xt * tanhf(xg);
    }
    __syncthreads();
    if (t < 32) {
        int bb = t >> 1, c = t & 1;
        float l0 = smod[bb][0 + c * 2 + 0] + 0.5f;
        float l1 = smod[bb][0 + c * 2 + 1];
        float br = smod[bb][4 + c * 2 + 0];
        float bi = smod[bb][4 + c * 2 + 1];
        float s0 = smod[bb][8 + c * 2 + 0] + 1.0f;
        float s1 = smod[bb][8 + c * 2 + 1];
        float omr = 1.0f - l0, omi = -l1;      // (1 - l)
        float Ar = s0 * omr - s1 * omi;
        float Ai = s0 * omi + s1 * omr;
        float Br = s0 * l0 - s1 * l1;
        float Bi = s0 * l1 + s1 * l0;
        float* p = par + (bb * 2 + c) * 6;
        p[0] = Ar; p[1] = Ai; p[2] = Br; p[3] = Bi; p[4] = br; p[5] = bi;
    }
}

// Kernel 2: streaming transform — IDENTICAL to R9 (best, 28.55us) except the
// output stores are NONTEMPORAL: the 64 MB write stream bypasses L2
// (no write-allocate + dirty-evict double handling), keeping L2/L3 clean
// for the read stream. Single-variable A/B vs R9.
__global__ __launch_bounds__(256) void main_kernel(
    const float* __restrict__ wts,   // [2][2][HW][2]
    const float* __restrict__ par,   // [16][2][6] = 192 floats
    float* __restrict__ out)         // [16][HW]
{
    const int t = threadIdx.x;
    const int idx = blockIdx.x * 256 + t;    // 0 .. HW/4 - 1 (4 px/thread)
    const float4* w4 = (const float4*)wts;   // [jc][HW/2] float4s

    float4 Wv[4][2];
#pragma unroll
    for (int jc = 0; jc < 4; ++jc) {
        Wv[jc][0] = w4[jc * (HW / 2) + idx * 2 + 0];
        Wv[jc][1] = w4[jc * (HW / 2) + idx * 2 + 1];
    }
    const float* w00 = (const float*)Wv[0];  // j=0, c=0
    const float* w01 = (const float*)Wv[1];  // j=0, c=1
    const float* w10 = (const float*)Wv[2];  // j=1, c=0
    const float* w11 = (const float*)Wv[3];  // j=1, c=1

    fx4* out4 = (fx4*)out;
#pragma unroll
    for (int b = 0; b < BATCH; ++b) {
        // uniform indices (no threadIdx) -> s_load from constant cache
        const float* p0 = par + (b * 2 + 0) * 6;
        const float* p1 = par + (b * 2 + 1) * 6;
        float A0r = p0[0], A0i = p0[1], B0r = p0[2], B0i = p0[3], c0r = p0[4], c0i = p0[5];
        float A1r = p1[0], A1i = p1[1], B1r = p1[2], B1i = p1[3], c1r = p1[4], c1i = p1[5];

        fx4 o;
#pragma unroll
        for (int p = 0; p < 4; ++p) {
            float a0r = w00[p * 2], a0i = w00[p * 2 + 1];
            float b0r = w10[p * 2], b0i = w10[p * 2 + 1];
            float a1r = w01[p * 2], a1i = w01[p * 2 + 1];
            float b1r = w11[p * 2], b1i = w11[p * 2 + 1];
            float z0r = c0r + A0r * a0r - A0i * a0i + B0r * b0r - B0i * b0i;
            float z0i = c0i + A0r * a0i + A0i * a0r + B0r * b0i + B0i * b0r;
            float z1r = c1r + A1r * a1r - A1i * a1i + B1r * b1r - B1i * b1i;
            float z1i = c1i + A1r * a1i + A1i * a1r + B1r * b1i + B1i * b1r;
            float rs = rsqrtf(z1r * z1r + z1i * z1i + 1e-12f);
            o[p] = (z0r * z1r + z0i * z1i) * rs;
        }
        __builtin_nontemporal_store(o, &out4[b * (HW / 4) + idx]);
    }
}

extern "C" void kernel_launch(void* const* d_in, const int* in_sizes, int n_in,
                              void* d_out, int out_size, void* d_ws, size_t ws_size,
                              hipStream_t stream) {
    const float* x      = (const float*)d_in[0];
    const float* W_in   = (const float*)d_in[1];
    const float* b_in   = (const float*)d_in[2];
    const float* W_gate = (const float*)d_in[3];
    const float* b_gate = (const float*)d_in[4];
    const float* wts    = (const float*)d_in[5];
    float* out = (float*)d_out;
    float* par = (float*)d_ws;

    params_kernel<<<1, 192, 0, stream>>>(x, W_in, b_in, W_gate, b_gate, par);
    main_kernel<<<1024, 256, 0, stream>>>(wts, par, out);
}